// Round 2
// baseline (814.558 us; speedup 1.0000x reference)
//
#include <hip/hip_runtime.h>

// Problem constants
#define TPB 384          // 6 waves; each wave's two 32-lane halves own q-subsets
#define BPB 32           // batches per block (b = lane & 31)
#define NQ 25
#define ND 9
#define XWORDS (BPB * NQ * ND)   // 7200 floats staged per block
#define X4 (XWORDS / 4)          // 1800 float4
#define SMEM_WORDS 8000          // 32000 bytes static LDS -> 5 blocks/CU (30 waves)
#define LOG2E 1.44269504088896340736f
#define C2 (40.0f * LOG2E)       // softmax shift, log2 domain

typedef _Float16 h2 __attribute__((ext_vector_type(2)));
typedef float f2 __attribute__((ext_vector_type(2)));
typedef float f4 __attribute__((ext_vector_type(4)));

__device__ __forceinline__ float dot2acc(h2 a, h2 b, float c) {
#if __has_builtin(__builtin_amdgcn_fdot2)
    return __builtin_amdgcn_fdot2(a, b, c, false);
#else
    return c + (float)a[0] * (float)b[0] + (float)a[1] * (float)b[1];
#endif
}

__device__ __forceinline__ float fast_exp2(float x) {
#if __has_builtin(__builtin_amdgcn_exp2f)
    return __builtin_amdgcn_exp2f(x);
#else
    return exp2f(x);
#endif
}

// Segment-aligned wave->q partition (seg wave-uniform => SGPR weight pointers):
//   w0: seg0, h0={0,1}   h1={2}      w1: seg1, h0={3,4,5}    h1={6,7}
//   w2: seg1, h0={8,9,10} h1={11,12} w3: seg2, h0={13,14,15} h1={16,17}
//   w4: seg2, h0={18,19,20} h1={21,22}  w5: seg3, h0={23} h1={24}
__constant__ int SEGW[6]  = {0, 1, 1, 2, 2, 3};
__constant__ int QBASE[6] = {0, 3, 8, 13, 18, 23};
__constant__ int QHOFF[6] = {2, 3, 3, 3, 3, 1};   // h=1 start offset within group
__constant__ int QC0[6]   = {2, 3, 3, 3, 3, 1};   // q count for h=0
__constant__ int QC1[6]   = {1, 2, 2, 2, 2, 1};   // q count for h=1

// LDS map (uint32 words):
//   phase 1/2 & 5/6: x/y rows, word = b*225 + q*9 + d          (7200 words)
//   phase 3/4: K/V interleaved h2, word = hp*1600 + q*64 + 2b + {0=K,1=V} (8000 words)
__global__ __launch_bounds__(TPB, 8) void attn_fused(
    const float* __restrict__ x,
    const float* __restrict__ Wjk, const float* __restrict__ bjk,
    const float* __restrict__ Wok, const float* __restrict__ bok,
    const float* __restrict__ Wgk, const float* __restrict__ bgk,
    const float* __restrict__ Wbk, const float* __restrict__ bbk,
    const float* __restrict__ Wjv, const float* __restrict__ bjv,
    const float* __restrict__ Wov, const float* __restrict__ bov,
    const float* __restrict__ Wgv, const float* __restrict__ bgv,
    const float* __restrict__ Wbv, const float* __restrict__ bbv,
    const float* __restrict__ ln_g, const float* __restrict__ ln_b,
    float* __restrict__ out)
{
    __shared__ alignas(16) unsigned int sm[SMEM_WORDS];

    const int tid  = threadIdx.x;
    const int lane = tid & 63;
    const int b    = lane & 31;                                  // local batch
    const int h    = lane >> 5;                                  // half-wave id
    const int w    = __builtin_amdgcn_readfirstlane(tid >> 6);   // wave id 0..5 (uniform)
    const long base = (long)blockIdx.x * XWORDS;

    // ---- phase 1: coalesced stage of x chunk into LDS ----
    {
        const f4* src = (const f4*)(x + base);
        f4* dst = (f4*)sm;
        #pragma unroll
        for (int i = 0; i < 5; ++i) {
            int idx = tid + i * TPB;
            if (idx < X4) dst[idx] = src[idx];
        }
    }
    __syncthreads();

    const int seg = SEGW[w];                      // wave-uniform
    const int qs  = QBASE[w] + h * QHOFF[w];      // per-half
    const int qc  = h ? QC1[w] : QC0[w];          // per-half (<=3)

    // ---- phase 2: read my x rows (stride 225 % 32 == 1 -> conflict-free) ----
    float xr[3][9];
    #pragma unroll
    for (int j = 0; j < 3; ++j) {
        if (j < qc) {
            const float* xsrc = (const float*)sm + b * (NQ * ND) + (qs + j) * ND;
            #pragma unroll
            for (int d = 0; d < ND; ++d) xr[j][d] = xsrc[d];
        }
    }
    __syncthreads();   // all x reads done before K/V overwrite the region

    // ---- phase 3: K,V projections (SGPR weights, seg wave-uniform), pack fp16 ----
    const float* Wk = (seg == 0) ? Wjk : (seg == 1) ? Wok : (seg == 2) ? Wgk : Wbk;
    const float* bk = (seg == 0) ? bjk : (seg == 1) ? bok : (seg == 2) ? bgk : bbk;
    const float* Wv = (seg == 0) ? Wjv : (seg == 1) ? Wov : (seg == 2) ? Wgv : Wbv;
    const float* bv = (seg == 0) ? bjv : (seg == 1) ? bov : (seg == 2) ? bgv : bbv;

    h2 kreg[3][5];
    #pragma unroll
    for (int j = 0; j < 3; ++j) {
        if (j < qc) {
            const int q = qs + j;   // per-half, but seg (=> weights) uniform
            float kk[9], vv[9];
            #pragma unroll
            for (int o = 0; o < ND; ++o) {
                float ak = bk[o];
                float av = bv[o];
                #pragma unroll
                for (int i = 0; i < ND; ++i) {
                    ak += Wk[o * ND + i] * xr[j][i];
                    av += Wv[o * ND + i] * xr[j][i];
                }
                kk[o] = ak; vv[o] = av;
            }
            #pragma unroll
            for (int hp = 0; hp < 5; ++hp) {
                float k0 = kk[2 * hp], k1 = (hp < 4) ? kk[2 * hp + 1] : 0.0f;
                float v0 = vv[2 * hp], v1 = (hp < 4) ? vv[2 * hp + 1] : 0.0f;
                h2 kh; kh[0] = (_Float16)k0; kh[1] = (_Float16)k1;
                h2 vh; vh[0] = (_Float16)v0; vh[1] = (_Float16)v1;
                h2 ks; ks[0] = (_Float16)(k0 * LOG2E); ks[1] = (_Float16)(k1 * LOG2E);
                kreg[j][hp] = ks;
                // K,V interleaved -> single ds_write_b64
                uint2 kv;
                kv.x = __builtin_bit_cast(unsigned int, kh);
                kv.y = __builtin_bit_cast(unsigned int, vh);
                *reinterpret_cast<uint2*>(sm + hp * 1600 + q * 64 + 2 * b) = kv;
            }
        }
    }
    __syncthreads();

    // ---- phase 4: fused scores + shifted-softmax(exp2 domain) + PV ----
    f2 res2[3][5];
    float lsum[3];
    #pragma unroll
    for (int j = 0; j < 3; ++j) {
        lsum[j] = 0.0f;
        #pragma unroll
        for (int hp = 0; hp < 5; ++hp) { res2[j][hp][0] = 0.0f; res2[j][hp][1] = 0.0f; }
    }

    #pragma unroll 1
    for (int k = 0; k < NQ; ++k) {
        h2 kh[5], vh[5];
        #pragma unroll
        for (int hp = 0; hp < 5; ++hp) {
            // one ds_read_b64 pulls the (K,V) h2 pair; halves broadcast same addr
            uint2 kv = *reinterpret_cast<const uint2*>(sm + hp * 1600 + k * 64 + 2 * b);
            kh[hp] = __builtin_bit_cast(h2, kv.x);
            vh[hp] = __builtin_bit_cast(h2, kv.y);
        }
        f2 vf2[5];
        #pragma unroll
        for (int hp = 0; hp < 5; ++hp) {
            vf2[hp][0] = (float)vh[hp][0];
            vf2[hp][1] = (float)vh[hp][1];
        }

        #pragma unroll
        for (int j = 0; j < 3; ++j) {
            if (j < qc) {
                float s = -C2;                       // shift folded into dot init
                #pragma unroll
                for (int hp = 0; hp < 5; ++hp) s = dot2acc(kreg[j][hp], kh[hp], s);
                float e = fast_exp2(s);              // exp(raw_s - 40)
                lsum[j] += e;
                f2 e2; e2[0] = e; e2[1] = e;
                #pragma unroll
                for (int hp = 0; hp < 5; ++hp) res2[j][hp] += e2 * vf2[hp];  // v_pk_fma_f32
            }
        }
    }
    __syncthreads();   // all K/V reads done before y overwrites the region

    // ---- phase 5: residual + LayerNorm, write y rows to LDS ----
    float g[9], bb[9];
    #pragma unroll
    for (int d = 0; d < ND; ++d) { g[d] = ln_g[d]; bb[d] = ln_b[d]; }

    #pragma unroll
    for (int j = 0; j < 3; ++j) {
        if (j < qc) {
            float res[9];
            #pragma unroll
            for (int hp = 0; hp < 4; ++hp) {
                res[2 * hp]     = res2[j][hp][0];
                res[2 * hp + 1] = res2[j][hp][1];
            }
            res[8] = res2[j][4][0];

            float rl = __builtin_amdgcn_rcpf(lsum[j]);
            float y[9];
            float s = 0.0f;
            #pragma unroll
            for (int d = 0; d < ND; ++d) {
                y[d] = xr[j][d] + res[d] * rl;
                s += y[d];
            }
            float mu = s * (1.0f / 9.0f);
            float var = 0.0f;
            #pragma unroll
            for (int d = 0; d < ND; ++d) {
                float t = y[d] - mu;
                var += t * t;
            }
            float rs = __builtin_amdgcn_rsqf(var * (1.0f / 9.0f) + 1e-5f);
            float* ydst = (float*)sm + b * (NQ * ND) + (qs + j) * ND;
            #pragma unroll
            for (int d = 0; d < ND; ++d) ydst[d] = (y[d] - mu) * rs * g[d] + bb[d];
        }
    }
    __syncthreads();

    // ---- phase 6: coalesced nontemporal store of y chunk ----
    {
        const f4* srcs = (const f4*)sm;
        f4* dstg = (f4*)(out + base);
        #pragma unroll
        for (int i = 0; i < 5; ++i) {
            int idx = tid + i * TPB;
            if (idx < X4) __builtin_nontemporal_store(srcs[idx], &dstg[idx]);
        }
    }
}

extern "C" void kernel_launch(void* const* d_in, const int* in_sizes, int n_in,
                              void* d_out, int out_size, void* d_ws, size_t ws_size,
                              hipStream_t stream) {
    const float* x   = (const float*)d_in[0];
    const float* Wjk = (const float*)d_in[1];
    const float* bjk = (const float*)d_in[2];
    const float* Wok = (const float*)d_in[3];
    const float* bok = (const float*)d_in[4];
    const float* Wgk = (const float*)d_in[5];
    const float* bgk = (const float*)d_in[6];
    const float* Wbk = (const float*)d_in[7];
    const float* bbk = (const float*)d_in[8];
    const float* Wjv = (const float*)d_in[9];
    const float* bjv = (const float*)d_in[10];
    const float* Wov = (const float*)d_in[11];
    const float* bov = (const float*)d_in[12];
    const float* Wgv = (const float*)d_in[13];
    const float* bgv = (const float*)d_in[14];
    const float* Wbv = (const float*)d_in[15];
    const float* bbv = (const float*)d_in[16];
    const float* lng = (const float*)d_in[17];
    const float* lnb = (const float*)d_in[18];
    float* out = (float*)d_out;

    const int nbatch = in_sizes[0] / (NQ * ND);      // 262144
    const int nblocks = nbatch / BPB;                // 8192

    hipLaunchKernelGGL(attn_fused, dim3(nblocks), dim3(TPB), 0, stream,
                       x, Wjk, bjk, Wok, bok, Wgk, bgk, Wbk, bbk,
                       Wjv, bjv, Wov, bov, Wgv, bgv, Wbv, bbv, lng, lnb, out);
}

// Round 3
// 490.285 us; speedup vs baseline: 1.6614x; 1.6614x over previous
//
#include <hip/hip_runtime.h>

// Problem constants
#define TPB 512          // 8 waves; each 32-lane half owns <=2 queries
#define BPB 32           // batches per block (b = lane & 31)
#define NQ 25
#define ND 9
#define XWORDS (BPB * NQ * ND)   // 7200 floats staged per block
#define X4 (XWORDS / 4)          // 1800 float4
#define SMEM_WORDS 8000          // 32000 bytes static LDS -> 4 blocks/CU (32 waves, 100%)
#define LOG2E 1.44269504088896340736f
#define C2 (40.0f * LOG2E)       // softmax shift, log2 domain

typedef _Float16 h2 __attribute__((ext_vector_type(2)));
typedef float f2 __attribute__((ext_vector_type(2)));
typedef float f4 __attribute__((ext_vector_type(4)));

__device__ __forceinline__ float dot2acc(h2 a, h2 b, float c) {
#if __has_builtin(__builtin_amdgcn_fdot2)
    return __builtin_amdgcn_fdot2(a, b, c, false);
#else
    return c + (float)a[0] * (float)b[0] + (float)a[1] * (float)b[1];
#endif
}

__device__ __forceinline__ float fast_exp2(float x) {
#if __has_builtin(__builtin_amdgcn_exp2f)
    return __builtin_amdgcn_exp2f(x);
#else
    return exp2f(x);
#endif
}

// Seg-pure wave->q partition, <=2 q per 32-lane half (keeps kreg/res2 small):
//   w0 seg0: {0,1}|{2}      w1 seg1: {3,4}|{5,6}   w2 seg1: {7,8}|{9,10}
//   w3 seg1: {11,12}|{}     w4 seg2: {13,14}|{15,16}
//   w5 seg2: {17,18}|{19,20} w6 seg2: {21,22}|{}   w7 seg3: {23}|{24}
__constant__ int SEGW[8] = {0, 1, 1, 1, 2, 2, 2, 3};
__constant__ int QS0[8]  = {0, 3, 7, 11, 13, 17, 21, 23};
__constant__ int QS1[8]  = {2, 5, 9,  0, 15, 19,  0, 24};
__constant__ int QC0[8]  = {2, 2, 2,  2,  2,  2,  2,  1};
__constant__ int QC1[8]  = {1, 2, 2,  0,  2,  2,  0,  1};

// LDS map (uint32 words):
//   phase 1/2 & 4.5/5/6: x/y rows, word = b*225 + q*9 + d      (7200 words)
//   phase 3/4: K/V interleaved h2, word = hp*1600 + q*64 + 2b + {0=K,1=V} (8000 words)
// empirical launch-bounds law on this compiler: VGPR cap = 256/arg2 -> arg2=4 => 64
__global__ __launch_bounds__(TPB, 4) void attn_fused(
    const float* __restrict__ x,
    const float* __restrict__ Wjk, const float* __restrict__ bjk,
    const float* __restrict__ Wok, const float* __restrict__ bok,
    const float* __restrict__ Wgk, const float* __restrict__ bgk,
    const float* __restrict__ Wbk, const float* __restrict__ bbk,
    const float* __restrict__ Wjv, const float* __restrict__ bjv,
    const float* __restrict__ Wov, const float* __restrict__ bov,
    const float* __restrict__ Wgv, const float* __restrict__ bgv,
    const float* __restrict__ Wbv, const float* __restrict__ bbv,
    const float* __restrict__ ln_g, const float* __restrict__ ln_b,
    float* __restrict__ out)
{
    __shared__ alignas(16) unsigned int sm[SMEM_WORDS];

    const int tid  = threadIdx.x;
    const int lane = tid & 63;
    const int b    = lane & 31;                                  // local batch
    const int h    = lane >> 5;                                  // half-wave id
    const int w    = __builtin_amdgcn_readfirstlane(tid >> 6);   // wave id 0..7 (uniform)
    const long base = (long)blockIdx.x * XWORDS;

    // ---- phase 1: coalesced stage of x chunk into LDS ----
    {
        const f4* src = (const f4*)(x + base);
        f4* dst = (f4*)sm;
        #pragma unroll
        for (int i = 0; i < 4; ++i) {
            int idx = tid + i * TPB;
            if (idx < X4) dst[idx] = src[idx];
        }
    }
    __syncthreads();

    const int seg = SEGW[w];                      // wave-uniform -> SGPR weights
    const int qs  = h ? QS1[w] : QS0[w];          // per-half
    const int qc  = h ? QC1[w] : QC0[w];          // per-half (<=2)

    // ---- phase 2: read my x rows (stride 225 % 32 == 1 -> conflict-free) ----
    // xr lives ONLY through phase 3 (x is re-staged for phase 5) -> low reg pressure
    float xr[2][9];
    #pragma unroll
    for (int j = 0; j < 2; ++j) {
        if (j < qc) {
            const float* xsrc = (const float*)sm + b * (NQ * ND) + (qs + j) * ND;
            #pragma unroll
            for (int d = 0; d < ND; ++d) xr[j][d] = xsrc[d];
        }
    }
    __syncthreads();   // all x reads done before K/V overwrite the region

    // ---- phase 3: K,V projections (SGPR weights, seg wave-uniform), pack fp16 ----
    const float* Wk = (seg == 0) ? Wjk : (seg == 1) ? Wok : (seg == 2) ? Wgk : Wbk;
    const float* bk = (seg == 0) ? bjk : (seg == 1) ? bok : (seg == 2) ? bgk : bbk;
    const float* Wv = (seg == 0) ? Wjv : (seg == 1) ? Wov : (seg == 2) ? Wgv : Wbv;
    const float* bv = (seg == 0) ? bjv : (seg == 1) ? bov : (seg == 2) ? bgv : bbv;

    h2 kreg[2][5];
    #pragma unroll
    for (int j = 0; j < 2; ++j) {
        if (j < qc) {
            const int q = qs + j;
            float kk[9], vv[9];
            #pragma unroll
            for (int o = 0; o < ND; ++o) {
                float ak = bk[o];
                float av = bv[o];
                #pragma unroll
                for (int i = 0; i < ND; ++i) {
                    ak += Wk[o * ND + i] * xr[j][i];
                    av += Wv[o * ND + i] * xr[j][i];
                }
                kk[o] = ak; vv[o] = av;
            }
            #pragma unroll
            for (int hp = 0; hp < 5; ++hp) {
                float k0 = kk[2 * hp], k1 = (hp < 4) ? kk[2 * hp + 1] : 0.0f;
                float v0 = vv[2 * hp], v1 = (hp < 4) ? vv[2 * hp + 1] : 0.0f;
                h2 kh; kh[0] = (_Float16)k0; kh[1] = (_Float16)k1;
                h2 vh; vh[0] = (_Float16)v0; vh[1] = (_Float16)v1;
                h2 ks; ks[0] = (_Float16)(k0 * LOG2E); ks[1] = (_Float16)(k1 * LOG2E);
                kreg[j][hp] = ks;
                uint2 kv;                                   // K,V pair -> one ds_write_b64
                kv.x = __builtin_bit_cast(unsigned int, kh);
                kv.y = __builtin_bit_cast(unsigned int, vh);
                *reinterpret_cast<uint2*>(sm + hp * 1600 + q * 64 + 2 * b) = kv;
            }
        }
    }
    __syncthreads();

    // ---- phase 4: fused scores + shifted-softmax(exp2 domain) + PV ----
    f2 res2[2][5];
    float lsum[2];
    #pragma unroll
    for (int j = 0; j < 2; ++j) {
        lsum[j] = 0.0f;
        #pragma unroll
        for (int hp = 0; hp < 5; ++hp) { res2[j][hp][0] = 0.0f; res2[j][hp][1] = 0.0f; }
    }

    #pragma unroll 1
    for (int k = 0; k < NQ; ++k) {
        h2 kh[5], vh[5];
        #pragma unroll
        for (int hp = 0; hp < 5; ++hp) {
            uint2 kv = *reinterpret_cast<const uint2*>(sm + hp * 1600 + k * 64 + 2 * b);
            kh[hp] = __builtin_bit_cast(h2, kv.x);
            vh[hp] = __builtin_bit_cast(h2, kv.y);
        }
        f2 vf2[5];
        #pragma unroll
        for (int hp = 0; hp < 5; ++hp) {
            vf2[hp][0] = (float)vh[hp][0];
            vf2[hp][1] = (float)vh[hp][1];
        }

        #pragma unroll
        for (int j = 0; j < 2; ++j) {
            if (j < qc) {
                float s = -C2;                       // shift folded into dot init
                #pragma unroll
                for (int hp = 0; hp < 5; ++hp) s = dot2acc(kreg[j][hp], kh[hp], s);
                float e = fast_exp2(s);              // exp(raw_s - 40)
                lsum[j] += e;
                f2 e2; e2[0] = e; e2[1] = e;
                #pragma unroll
                for (int hp = 0; hp < 5; ++hp) res2[j][hp] += e2 * vf2[hp];  // v_pk_fma_f32
            }
        }
    }
    __syncthreads();   // all K/V reads done before x re-stage overwrites the region

    // ---- phase 4.5: re-stage x into LDS (K/V region now dead; L3-warm read) ----
    {
        const f4* src = (const f4*)(x + base);
        f4* dst = (f4*)sm;
        #pragma unroll
        for (int i = 0; i < 4; ++i) {
            int idx = tid + i * TPB;
            if (idx < X4) dst[idx] = src[idx];
        }
    }
    __syncthreads();

    // ---- phase 5: residual + LayerNorm; y overwrites own x rows in place ----
    float g[9], bb[9];
    #pragma unroll
    for (int d = 0; d < ND; ++d) { g[d] = ln_g[d]; bb[d] = ln_b[d]; }

    #pragma unroll
    for (int j = 0; j < 2; ++j) {
        if (j < qc) {
            float res[9];
            #pragma unroll
            for (int hp = 0; hp < 4; ++hp) {
                res[2 * hp]     = res2[j][hp][0];
                res[2 * hp + 1] = res2[j][hp][1];
            }
            res[8] = res2[j][4][0];

            float* xrow = (float*)sm + b * (NQ * ND) + (qs + j) * ND;
            float rl = __builtin_amdgcn_rcpf(lsum[j]);
            float y[9];
            float s = 0.0f;
            #pragma unroll
            for (int d = 0; d < ND; ++d) {
                y[d] = xrow[d] + res[d] * rl;
                s += y[d];
            }
            float mu = s * (1.0f / 9.0f);
            float var = 0.0f;
            #pragma unroll
            for (int d = 0; d < ND; ++d) {
                float t = y[d] - mu;
                var += t * t;
            }
            float rs = __builtin_amdgcn_rsqf(var * (1.0f / 9.0f) + 1e-5f);
            #pragma unroll
            for (int d = 0; d < ND; ++d) xrow[d] = (y[d] - mu) * rs * g[d] + bb[d];
        }
    }
    __syncthreads();

    // ---- phase 6: coalesced nontemporal store of y chunk ----
    {
        const f4* srcs = (const f4*)sm;
        f4* dstg = (f4*)(out + base);
        #pragma unroll
        for (int i = 0; i < 4; ++i) {
            int idx = tid + i * TPB;
            if (idx < X4) __builtin_nontemporal_store(srcs[idx], &dstg[idx]);
        }
    }
}

extern "C" void kernel_launch(void* const* d_in, const int* in_sizes, int n_in,
                              void* d_out, int out_size, void* d_ws, size_t ws_size,
                              hipStream_t stream) {
    const float* x   = (const float*)d_in[0];
    const float* Wjk = (const float*)d_in[1];
    const float* bjk = (const float*)d_in[2];
    const float* Wok = (const float*)d_in[3];
    const float* bok = (const float*)d_in[4];
    const float* Wgk = (const float*)d_in[5];
    const float* bgk = (const float*)d_in[6];
    const float* Wbk = (const float*)d_in[7];
    const float* bbk = (const float*)d_in[8];
    const float* Wjv = (const float*)d_in[9];
    const float* bjv = (const float*)d_in[10];
    const float* Wov = (const float*)d_in[11];
    const float* bov = (const float*)d_in[12];
    const float* Wgv = (const float*)d_in[13];
    const float* bgv = (const float*)d_in[14];
    const float* Wbv = (const float*)d_in[15];
    const float* bbv = (const float*)d_in[16];
    const float* lng = (const float*)d_in[17];
    const float* lnb = (const float*)d_in[18];
    float* out = (float*)d_out;

    const int nbatch = in_sizes[0] / (NQ * ND);      // 262144
    const int nblocks = nbatch / BPB;                // 8192

    hipLaunchKernelGGL(attn_fused, dim3(nblocks), dim3(TPB), 0, stream,
                       x, Wjk, bjk, Wok, bok, Wgk, bgk, Wbk, bbk,
                       Wjv, bjv, Wov, bov, Wgv, bgv, Wbv, bbv, lng, lnb, out);
}